// Round 13
// baseline (206.113 us; speedup 1.0000x reference)
//
#include <hip/hip_runtime.h>
#include <hip/hip_bf16.h>
#include <math.h>

#define Hd 128
#define Tt 256
#define Bb 1024
#define CL 32           // time-chunk length
#define NCK (Tt / CL)   // 8 chunks

typedef __attribute__((ext_vector_type(8))) short short8;
typedef __attribute__((ext_vector_type(4))) float f32x4;

__device__ __forceinline__ short f2bf(float f) {
    unsigned u = __float_as_uint(f);
    u += 0x7fffu + ((u >> 16) & 1u);   // RNE
    return (short)(u >> 16);
}
__device__ __forceinline__ f32x4 spl(float v) { f32x4 a = {v, v, v, v}; return a; }

// pack 8 f32 -> short8 of bf16 via v_cvt_pk_bf16_f32 (RNE)
__device__ __forceinline__ short8 cvt8(f32x4 a, f32x4 b) {
    union { unsigned u[4]; short8 s; } c;
    asm("v_cvt_pk_bf16_f32 %0, %1, %2" : "=v"(c.u[0]) : "v"(a[0]), "v"(a[1]));
    asm("v_cvt_pk_bf16_f32 %0, %1, %2" : "=v"(c.u[1]) : "v"(a[2]), "v"(a[3]));
    asm("v_cvt_pk_bf16_f32 %0, %1, %2" : "=v"(c.u[2]) : "v"(b[0]), "v"(b[1]));
    asm("v_cvt_pk_bf16_f32 %0, %1, %2" : "=v"(c.u[3]) : "v"(b[2]), "v"(b[3]));
    return c.s;
}

// Weights -> bf16 MFMA B-frag layout [nt][kf][lane][8].  (verbatim)
__global__ void prep_weights(const float* __restrict__ Wih,
                             const float* __restrict__ Whh,
                             const float* __restrict__ fcW,
                             short* __restrict__ oIh, short* __restrict__ oHh,
                             short* __restrict__ oFc) {
    int t = blockIdx.x * 256 + threadIdx.x;
    if (t >= 14336) return;
    const float* src;
    short* dst;
    if (t < 6144)       { src = Wih; dst = oIh + t * 8; }
    else if (t < 12288) { t -= 6144;  src = Whh; dst = oHh + t * 8; }
    else                { t -= 12288; src = fcW; dst = oFc + t * 8; }
    int lane = t & 63, kf = (t >> 6) & 3, nt = t >> 8;
    const float* s = src + (nt * 16 + (lane & 15)) * 128 + kf * 32 + 8 * (lane >> 4);
#pragma unroll
    for (int j = 0; j < 8; j++) dst[j] = f2bf(s[j]);
}

// Fused recurrence: xi computed IN-STEP (R13). Eliminates the 201 MB xi
// intermediate (R12: xi_gemm 93 us write-bound + 111 MB re-read in gru).
// Per step: gather x_t A-frags (cvt'd at END of previous step -> load latency
// hidden), stream W_ih B-frags from L2 (2-buffer tile pipeline, 32 transient
// regs; FC block hides first tiles' latency), 24 xi-MFMAs. n-gate xi goes to
// SEPARATE axn accumulators (n = tanh(xn + r*gh_n)); r/z xi folds into acc.
#define LOADW(W, i_) { const short* wb_ = wIh + ((j + 4 * (i_)) * 2048 + ln * 8); \
    W[0] = *(const short8*)(wb_);        W[1] = *(const short8*)(wb_ + 512);      \
    W[2] = *(const short8*)(wb_ + 1024); W[3] = *(const short8*)(wb_ + 1536); }
#define XITILE(ACC, W) { \
    ACC = __builtin_amdgcn_mfma_f32_16x16x32_bf16(xfrag[0], W[0], ACC, 0, 0, 0); \
    ACC = __builtin_amdgcn_mfma_f32_16x16x32_bf16(xfrag[1], W[1], ACC, 0, 0, 0); \
    ACC = __builtin_amdgcn_mfma_f32_16x16x32_bf16(xfrag[2], W[2], ACC, 0, 0, 0); \
    ACC = __builtin_amdgcn_mfma_f32_16x16x32_bf16(xfrag[3], W[3], ACC, 0, 0, 0); }

__global__ __launch_bounds__(256)
void gru_fused(const float* __restrict__ x, const int* __restrict__ done,
               const float* __restrict__ h0, const float* __restrict__ bih,
               const float* __restrict__ bhh, const float* __restrict__ fcb,
               const short* __restrict__ wIh, const short* __restrict__ wHh,
               const short* __restrict__ wFc,
               float* __restrict__ out, float* __restrict__ hlast) {
    __shared__ short hT[2][16 * 136];
    __shared__ int doneL[Tt * 16];
    __shared__ int rbL[16];
    const int tid = threadIdx.x, j = tid >> 6, ln = tid & 63;
    const int q = ln & 15, lg = ln >> 4;
    const int bg = blockIdx.x, ck = blockIdx.y;
    const int t_c = ck * CL, t_end = t_c + CL;

    {   // stage done[b][0..t_end) -> doneL[t][b]
        const int b = tid >> 4, i = tid & 15;
        const int* dp = done + (size_t)(bg * 16 + b) * Tt;
        for (int t = i; t < t_end; t += 16) doneL[t * 16 + b] = dp[t];
    }
    __syncthreads();
    if (tid < 16) {   // last reset before t_c
        int r = 0;
        for (int t = t_c - 1; t >= 0; --t)
            if (doneL[t * 16 + tid]) { r = t + 1; break; }
        rbL[tid] = r;
    }
    __syncthreads();
    int rmin = rbL[0];
#pragma unroll
    for (int b = 1; b < 16; b++) rmin = min(rmin, rbL[b]);

    short8 whh[6][4], wfc[2][4];
#pragma unroll
    for (int i = 0; i < 6; i++)
#pragma unroll
        for (int kf = 0; kf < 4; kf++)
            whh[i][kf] = *(const short8*)&wHh[(((j + 4 * i) * 4 + kf) * 64 + ln) * 8];
#pragma unroll
    for (int cs = 0; cs < 2; cs++)
#pragma unroll
        for (int kf = 0; kf < 4; kf++)
            wfc[cs][kf] = *(const short8*)&wFc[(((j + 4 * cs) * 4 + kf) * 64 + ln) * 8];
    float br[2], bz[2], bxn[2], cbn[2], cbf[2];
#pragma unroll
    for (int cs = 0; cs < 2; cs++) {
        int c = 16 * j + 64 * cs + q;
        br[cs]  = bih[c] + bhh[c];
        bz[cs]  = bih[128 + c] + bhh[128 + c];
        bxn[cs] = bih[256 + c];
        cbn[cs] = bhh[256 + c];
        cbf[cs] = fcb[c];
    }

    float h_reg[2][4];
#pragma unroll
    for (int cs = 0; cs < 2; cs++)
#pragma unroll
        for (int r = 0; r < 4; r++) {
            int bb = 4 * lg + r, c = 16 * j + 64 * cs + q;
            h_reg[cs][r] = (rbL[bb] == 0) ? h0[(size_t)(bg * 16 + bb) * Hd + c] : 0.f;
        }
    {   // hT[rmin&1] <- h_init (h0 if r_b==0 else 0)
        int row = tid >> 4, c0 = (tid & 15) * 8;
        short8 s0 = {0,0,0,0,0,0,0,0};
        if (rbL[row] == 0) {
            const float* hp = &h0[(size_t)(bg * 16 + row) * Hd + c0];
            f32x4 u0 = *(const f32x4*)&hp[0], u1 = *(const f32x4*)&hp[4];
#pragma unroll
            for (int i = 0; i < 4; i++) { s0[i] = f2bf(u0[i]); s0[i+4] = f2bf(u1[i]); }
        }
        *(short8*)&hT[rmin & 1][row * 136 + c0] = s0;
    }
    __syncthreads();

    // x A-frag pointer: lane (q,lg) reads row bg*16+q, cols kf*32+8lg..+8
    const float* xq = x + ((size_t)(bg * 16 + q) * Tt + rmin) * Hd + 8 * lg;
    short8 xfrag[4];
    {   // prologue: load+convert frame rmin (one exposed stall)
        f32x4 xv0[8];
#pragma unroll
        for (int kf = 0; kf < 4; kf++) {
            xv0[2 * kf]     = *(const f32x4*)(xq + kf * 32);
            xv0[2 * kf + 1] = *(const f32x4*)(xq + kf * 32 + 4);
        }
#pragma unroll
        for (int kf = 0; kf < 4; kf++) xfrag[kf] = cvt8(xv0[2 * kf], xv0[2 * kf + 1]);
    }

#pragma unroll 1
    for (int t = rmin; t < t_end; ++t) {
        const short* hTp = &hT[t & 1][0];
        short* hTn = &hT[(t + 1) & 1][0];
        short8 haf[4];
#pragma unroll
        for (int kf = 0; kf < 4; kf++)
            haf[kf] = *(const short8*)&hTp[q * 136 + kf * 32 + 8 * lg];

        // W_ih pipeline prefill (tiles 0,1) -- FC below hides their L2 latency
        short8 wA[4], wB[4];
        LOADW(wA, 0); LOADW(wB, 1);

        // x loads for t+1 (issued BEFORE this step's stores: vmcnt order)
        xq += Hd;
        f32x4 xv[8];
        if (t + 1 < t_end) {
#pragma unroll
            for (int kf = 0; kf < 4; kf++) {
                xv[2 * kf]     = *(const f32x4*)(xq + kf * 32);
                xv[2 * kf + 1] = *(const f32x4*)(xq + kf * 32 + 4);
            }
        }

        if (t > t_c) {   // FC+ELU+stores for frame t-1 (un-reset haf)
            f32x4 fca[2] = {spl(cbf[0]), spl(cbf[1])};
#pragma unroll
            for (int kf = 0; kf < 4; kf++)
#pragma unroll
                for (int cs = 0; cs < 2; cs++)
                    fca[cs] = __builtin_amdgcn_mfma_f32_16x16x32_bf16(haf[kf], wfc[cs][kf], fca[cs], 0, 0, 0);
#pragma unroll
            for (int cs = 0; cs < 2; cs++)
#pragma unroll
                for (int r = 0; r < 4; r++) {
                    int bb = 4 * lg + r, c = 16 * j + 64 * cs + q;
                    float v = fca[cs][r];
                    float e = __expf(v) - 1.f;
                    v = v > 0.f ? v : e;
                    out[(((size_t)(bg * 16 + bb)) * Tt + (t - 1)) * Hd + c] = v;
                }
        }

        // xi = x_t @ W_ih^T (+ biases): 2-buffer tile pipeline over 6 tiles
        f32x4 acc[6], axn[2];
        acc[0] = spl(br[0]); acc[1] = spl(br[1]);
        acc[2] = spl(bz[0]); acc[3] = spl(bz[1]);
        axn[0] = spl(bxn[0]); axn[1] = spl(bxn[1]);
        XITILE(acc[0], wA); LOADW(wA, 2);
        XITILE(acc[1], wB); LOADW(wB, 3);
        XITILE(acc[2], wA); LOADW(wA, 4);
        XITILE(acc[3], wB); LOADW(wB, 5);
        XITILE(axn[0], wA);
        XITILE(axn[1], wB);

        if (t > 0) {   // reset haf in place (FC above used un-reset value)
            int dn = doneL[(t - 1) * 16 + q];
            short8 z8 = {0,0,0,0,0,0,0,0};
#pragma unroll
            for (int kf = 0; kf < 4; kf++) haf[kf] = dn ? z8 : haf[kf];
        }
        acc[4] = spl(cbn[0]); acc[5] = spl(cbn[1]);
        __builtin_amdgcn_s_setprio(1);   // favor the h-critical region
#pragma unroll
        for (int kf = 0; kf < 4; kf++)
#pragma unroll
            for (int i = 0; i < 6; i++)
                acc[i] = __builtin_amdgcn_mfma_f32_16x16x32_bf16(haf[kf], whh[i][kf], acc[i], 0, 0, 0);

        float rstf[4] = {1.f, 1.f, 1.f, 1.f};
        if (t > 0) {
            int4 dd = *(const int4*)&doneL[(t - 1) * 16 + 4 * lg];
            rstf[0] = dd.x ? 0.f : 1.f; rstf[1] = dd.y ? 0.f : 1.f;
            rstf[2] = dd.z ? 0.f : 1.f; rstf[3] = dd.w ? 0.f : 1.f;
        }
#pragma unroll
        for (int cs = 0; cs < 2; cs++) {
#pragma unroll
            for (int r = 0; r < 4; r++) {
                float rg = __builtin_amdgcn_rcpf(1.f + __expf(-acc[cs][r]));
                float zg = __builtin_amdgcn_rcpf(1.f + __expf(-acc[2 + cs][r]));
                float xn = axn[cs][r];   // f32 now (was bf16 round-trip)
                float aa = fmaf(rg, acc[4 + cs][r], xn);
                float ng = 1.f - 2.f * __builtin_amdgcn_rcpf(__expf(2.f * aa) + 1.f);
                float hp = h_reg[cs][r] * rstf[r];
                float hn = (1.f - zg) * ng + zg * hp;
                h_reg[cs][r] = hn;                       // un-reset
                hTn[(4 * lg + r) * 136 + 16 * j + 64 * cs + q] = f2bf(hn);
            }
        }
        __builtin_amdgcn_s_setprio(0);
        if (t + 1 < t_end) {   // convert t+1's x (loads ~a full step old)
#pragma unroll
            for (int kf = 0; kf < 4; kf++) xfrag[kf] = cvt8(xv[2 * kf], xv[2 * kf + 1]);
        }
        // raw barrier: lgkmcnt(0) only (vmem stays in flight)
        __builtin_amdgcn_sched_barrier(0);
        __builtin_amdgcn_s_waitcnt(0xC07F);
        __builtin_amdgcn_s_barrier();
        __builtin_amdgcn_sched_barrier(0);
    }
    {   // epilogue FC for frame t_end-1 (slot t_end&1 holds h_{t_end-1})
        const short* hTp = &hT[t_end & 1][0];
        short8 haf[4];
#pragma unroll
        for (int kf = 0; kf < 4; kf++)
            haf[kf] = *(const short8*)&hTp[q * 136 + kf * 32 + 8 * lg];
        f32x4 fca[2] = {spl(cbf[0]), spl(cbf[1])};
#pragma unroll
        for (int kf = 0; kf < 4; kf++)
#pragma unroll
            for (int cs = 0; cs < 2; cs++)
                fca[cs] = __builtin_amdgcn_mfma_f32_16x16x32_bf16(haf[kf], wfc[cs][kf], fca[cs], 0, 0, 0);
#pragma unroll
        for (int cs = 0; cs < 2; cs++)
#pragma unroll
            for (int r = 0; r < 4; r++) {
                int bb = 4 * lg + r, c = 16 * j + 64 * cs + q;
                float v = fca[cs][r];
                float e = __expf(v) - 1.f;
                v = v > 0.f ? v : e;
                out[(((size_t)(bg * 16 + bb)) * Tt + (t_end - 1)) * Hd + c] = v;
            }
    }
    if (ck == NCK - 1) {   // h after step 255, un-reset
#pragma unroll
        for (int cs = 0; cs < 2; cs++)
#pragma unroll
            for (int r = 0; r < 4; r++) {
                int bb = 4 * lg + r, c = 16 * j + 64 * cs + q;
                hlast[(size_t)(bg * 16 + bb) * Hd + c] = h_reg[cs][r];
            }
    }
}

extern "C" void kernel_launch(void* const* d_in, const int* in_sizes, int n_in,
                              void* d_out, int out_size, void* d_ws, size_t ws_size,
                              hipStream_t stream) {
    const float* x   = (const float*)d_in[0];
    const float* h0  = (const float*)d_in[1];
    const int*   dn  = (const int*)d_in[2];
    const float* Wih = (const float*)d_in[3];
    const float* Whh = (const float*)d_in[4];
    const float* bih = (const float*)d_in[5];
    const float* bhh = (const float*)d_in[6];
    const float* fcW = (const float*)d_in[7];
    const float* fcb = (const float*)d_in[8];

    short* wIh = (short*)d_ws;                 // 96 KB
    short* wHh = wIh + 49152;                  // 96 KB
    short* wFc = wHh + 49152;                  // 32 KB
    float* out = (float*)d_out;
    float* hlast = out + (size_t)Bb * Tt * Hd;

    prep_weights<<<56, 256, 0, stream>>>(Wih, Whh, fcW, wIh, wHh, wFc);
    gru_fused<<<dim3(64, NCK), 256, 0, stream>>>(x, dn, h0, bih, bhh, fcb,
                                                 wIh, wHh, wFc, out, hlast);
}

// Round 14
// 184.338 us; speedup vs baseline: 1.1181x; 1.1181x over previous
//
#include <hip/hip_runtime.h>
#include <hip/hip_bf16.h>
#include <math.h>

#define Hd 128
#define Tt 256
#define Bb 1024
#define CL 32           // time-chunk length
#define NCK (Tt / CL)   // 8 chunks

typedef __attribute__((ext_vector_type(8))) short short8;
typedef __attribute__((ext_vector_type(4))) float f32x4;

__device__ __forceinline__ short f2bf(float f) {
    unsigned u = __float_as_uint(f);
    u += 0x7fffu + ((u >> 16) & 1u);   // RNE
    return (short)(u >> 16);
}
__device__ __forceinline__ float bflo(unsigned u) { return __uint_as_float(u << 16); }
__device__ __forceinline__ float bfhi(unsigned u) { return __uint_as_float(u & 0xffff0000u); }

// Weights -> bf16 MFMA B-frag layout [nt][kf][lane][8].  (verbatim)
__global__ void prep_weights(const float* __restrict__ Wih,
                             const float* __restrict__ Whh,
                             const float* __restrict__ fcW,
                             short* __restrict__ oIh, short* __restrict__ oHh,
                             short* __restrict__ oFc) {
    int t = blockIdx.x * 256 + threadIdx.x;
    if (t >= 14336) return;
    const float* src;
    short* dst;
    if (t < 6144)       { src = Wih; dst = oIh + t * 8; }
    else if (t < 12288) { t -= 6144;  src = Whh; dst = oHh + t * 8; }
    else                { t -= 12288; src = fcW; dst = oFc + t * 8; }
    int lane = t & 63, kf = (t >> 6) & 3, nt = t >> 8;
    const float* s = src + (nt * 16 + (lane & 15)) * 128 + kf * 32 + 8 * (lane >> 4);
#pragma unroll
    for (int j = 0; j < 8; j++) dst[j] = f2bf(s[j]);
}

// K2: xi = x@W_ih^T (+bih, +bhh for r/z cols) in C-frag order.
// R14: 8 frames per block (2048 blocks, was 4096) -- halves per-block W_ih
// L2 re-reads + fixed overheads; unroll 2 on mt for ILP. Layout unchanged.
__global__ __launch_bounds__(512)
void xi_gemm(const float* __restrict__ x, const float* __restrict__ bih,
             const float* __restrict__ bhh, const short* __restrict__ wIh,
             short* __restrict__ xi_l) {
    __shared__ short xs[128 * 136];        // 8 frames x 16 batches (34.8 KB)
    const int tid = threadIdx.x, wv = tid >> 6, ln = tid & 63;
    const int q = ln & 15, lg = ln >> 4;
    const int bg = blockIdx.x;
    const int sl0 = blockIdx.y * 8;
    {   // stage: row = dt*16 + b; thread stages 32 cols of one row
        const int row = tid >> 2, kq = tid & 3;
        const int b = row & 15, dt = row >> 4;
        const float* xp = x + (((size_t)(bg * 16 + b)) * Tt + (sl0 + dt)) * Hd + kq * 32;
        short* dp = &xs[row * 136 + kq * 32];
#pragma unroll
        for (int h = 0; h < 2; h++) {
            f32x4 u0 = *(const f32x4*)&xp[16 * h];
            f32x4 u1 = *(const f32x4*)&xp[16 * h + 4];
            f32x4 u2 = *(const f32x4*)&xp[16 * h + 8];
            f32x4 u3 = *(const f32x4*)&xp[16 * h + 12];
            short8 s0, s1;
#pragma unroll
            for (int i = 0; i < 4; i++) { s0[i] = f2bf(u0[i]); s0[i+4] = f2bf(u1[i]);
                                          s1[i] = f2bf(u2[i]); s1[i+4] = f2bf(u3[i]); }
            *(short8*)(dp + 16 * h) = s0;
            *(short8*)(dp + 16 * h + 8) = s1;
        }
    }
    __syncthreads();
    short8 wb[3][4];
#pragma unroll
    for (int i = 0; i < 3; i++)
#pragma unroll
        for (int kf = 0; kf < 4; kf++)
            wb[i][kf] = *(const short8*)&wIh[(((wv + 8 * i) * 4 + kf) * 64 + ln) * 8];
    float biasv[3];
#pragma unroll
    for (int i = 0; i < 3; i++) {
        int c = (wv + 8 * i) * 16 + q;
        biasv[i] = bih[c] + (c < 256 ? bhh[c] : 0.f);
    }
#pragma unroll 2
    for (int mt = 0; mt < 8; mt++) {
        short8 af[4];
#pragma unroll
        for (int kf = 0; kf < 4; kf++)
            af[kf] = *(const short8*)&xs[(mt * 16 + q) * 136 + kf * 32 + 8 * lg];
        f32x4 c0 = {0,0,0,0}, c1 = {0,0,0,0}, c2 = {0,0,0,0};
#pragma unroll
        for (int kf = 0; kf < 4; kf++) {
            c0 = __builtin_amdgcn_mfma_f32_16x16x32_bf16(af[kf], wb[0][kf], c0, 0, 0, 0);
            c1 = __builtin_amdgcn_mfma_f32_16x16x32_bf16(af[kf], wb[1][kf], c1, 0, 0, 0);
            c2 = __builtin_amdgcn_mfma_f32_16x16x32_bf16(af[kf], wb[2][kf], c2, 0, 0, 0);
        }
#pragma unroll
        for (int i = 0; i < 3; i++) {
            f32x4 cc = (i == 0) ? c0 : (i == 1) ? c1 : c2;
            unsigned d0 = (unsigned)(unsigned short)f2bf(cc[0] + biasv[i]) |
                          ((unsigned)(unsigned short)f2bf(cc[1] + biasv[i]) << 16);
            unsigned d1 = (unsigned)(unsigned short)f2bf(cc[2] + biasv[i]) |
                          ((unsigned)(unsigned short)f2bf(cc[3] + biasv[i]) << 16);
            uint2 dd = {d0, d1};
            ((uint2*)xi_l)[(((size_t)bg * Tt + (sl0 + mt)) * 24 + (wv + 8 * i)) * 64 + ln] = dd;
        }
    }
}

// K3: time-chunked recurrence. R14: 8-wave blocks (512 thr) at CL=32.
// Wave w owns gate cols 16w..16w+15 = gh tiles {w,w+8,w+16} + fc tile w:
// 64 weight VGPRs/wave (4-wave layout: 128 -> combined regs ~125 vs ~230)
// -> target 2x8-wave blocks/CU = 16 waves (was 8). R11's 8-wave regression
// was CL=16 depth + it lacked setprio; CL=32 fixes depth. + cvt_pk writeback.
__global__ __launch_bounds__(512)
void gru_chunk(const short* __restrict__ xi_l, const int* __restrict__ done,
               const float* __restrict__ h0,
               const float* __restrict__ bhh, const float* __restrict__ fcb,
               const short* __restrict__ wHh, const short* __restrict__ wFc,
               float* __restrict__ out, float* __restrict__ hlast) {
    __shared__ short hT[2][16 * 136];
    __shared__ int doneL[Tt * 16];
    __shared__ int rbL[16];
    const int tid = threadIdx.x, w = tid >> 6, ln = tid & 63;
    const int q = ln & 15, lg = ln >> 4;
    const int bg = blockIdx.x, ck = blockIdx.y;
    const int t_c = ck * CL, t_end = t_c + CL;
    const int c = 16 * w + q;          // this thread's gate/hidden column

    {   // stage done[b][0..t_end) -> doneL[t][b]
        const int b = tid >> 5, i = tid & 31;
        const int* dp = done + (size_t)(bg * 16 + b) * Tt;
        for (int t = i; t < t_end; t += 32) doneL[t * 16 + b] = dp[t];
    }
    __syncthreads();
    if (tid < 16) {   // last reset before t_c
        int r = 0;
        for (int t = t_c - 1; t >= 0; --t)
            if (doneL[t * 16 + tid]) { r = t + 1; break; }
        rbL[tid] = r;
    }
    __syncthreads();
    int rmin = rbL[0];
#pragma unroll
    for (int b = 1; b < 16; b++) rmin = min(rmin, rbL[b]);

    // per-wave weights: gh tiles {w, w+8, w+16} (i=0:r, 1:z, 2:n), fc tile w
    short8 whh[3][4], wfc[4];
#pragma unroll
    for (int i = 0; i < 3; i++)
#pragma unroll
        for (int kf = 0; kf < 4; kf++)
            whh[i][kf] = *(const short8*)&wHh[(((w + 8 * i) * 4 + kf) * 64 + ln) * 8];
#pragma unroll
    for (int kf = 0; kf < 4; kf++)
        wfc[kf] = *(const short8*)&wFc[((w * 4 + kf) * 64 + ln) * 8];
    const float cbn = bhh[256 + c];
    const float cbf = fcb[c];

    float h_reg[4];
#pragma unroll
    for (int r = 0; r < 4; r++) {
        int bb = 4 * lg + r;
        h_reg[r] = (rbL[bb] == 0) ? h0[(size_t)(bg * 16 + bb) * Hd + c] : 0.f;
    }
    if (tid < 256) {   // hT[rmin&1] <- h_init (h0 if r_b==0 else 0)
        int row = tid >> 4, c0 = (tid & 15) * 8;
        short8 s0 = {0,0,0,0,0,0,0,0};
        if (rbL[row] == 0) {
            const float* hp = &h0[(size_t)(bg * 16 + row) * Hd + c0];
            f32x4 u0 = *(const f32x4*)&hp[0], u1 = *(const f32x4*)&hp[4];
#pragma unroll
            for (int i = 0; i < 4; i++) { s0[i] = f2bf(u0[i]); s0[i+4] = f2bf(u1[i]); }
        }
        *(short8*)&hT[rmin & 1][row * 136 + c0] = s0;
    }
    __syncthreads();

    // xi: tile nt at uint2-offset nt*64 within a t-frame of 1536; tiles w+8i
    const uint2* xp = (const uint2*)xi_l + ((size_t)bg * Tt + rmin) * 1536 + w * 64 + ln;
    uint2 cur[3];
#pragma unroll
    for (int i = 0; i < 3; i++) cur[i] = xp[i * 512];
    xp += 1536;

#pragma unroll 1
    for (int t = rmin; t < t_end; ++t) {
        const short* hTp = &hT[t & 1][0];
        short* hTn = &hT[(t + 1) & 1][0];
        short8 haf[4];
#pragma unroll
        for (int kf = 0; kf < 4; kf++)
            haf[kf] = *(const short8*)&hTp[q * 136 + kf * 32 + 8 * lg];

        // consume cur(t) -> acc init + xn8; issue loads for t+1 (older than
        // this iter's stores in vmcnt order)
        f32x4 acc[3];
        { f32x4 a = {bflo(cur[0].x), bfhi(cur[0].x), bflo(cur[0].y), bfhi(cur[0].y)}; acc[0] = a; }
        { f32x4 a = {bflo(cur[1].x), bfhi(cur[1].x), bflo(cur[1].y), bfhi(cur[1].y)}; acc[1] = a; }
        { f32x4 a = {cbn, cbn, cbn, cbn}; acc[2] = a; }
        uint2 xn8 = cur[2];
        if (t + 1 < t_end) {
#pragma unroll
            for (int i = 0; i < 3; i++) cur[i] = xp[i * 512];
        }
        xp += 1536;

        if (t > t_c) {   // FC+ELU+stores for frame t-1 (un-reset haf)
            f32x4 fca = {cbf, cbf, cbf, cbf};
#pragma unroll
            for (int kf = 0; kf < 4; kf++)
                fca = __builtin_amdgcn_mfma_f32_16x16x32_bf16(haf[kf], wfc[kf], fca, 0, 0, 0);
#pragma unroll
            for (int r = 0; r < 4; r++) {
                int bb = 4 * lg + r;
                float v = fca[r];
                float e = __expf(v) - 1.f;
                v = v > 0.f ? v : e;
                out[(((size_t)(bg * 16 + bb)) * Tt + (t - 1)) * Hd + c] = v;
            }
        }

        if (t > 0) {   // reset haf in place (FC above used un-reset value)
            int dn = doneL[(t - 1) * 16 + q];
            short8 z8 = {0,0,0,0,0,0,0,0};
#pragma unroll
            for (int kf = 0; kf < 4; kf++) haf[kf] = dn ? z8 : haf[kf];
        }
        __builtin_amdgcn_s_setprio(1);   // favor the h-critical region
#pragma unroll
        for (int kf = 0; kf < 4; kf++) {
            acc[0] = __builtin_amdgcn_mfma_f32_16x16x32_bf16(haf[kf], whh[0][kf], acc[0], 0, 0, 0);
            acc[1] = __builtin_amdgcn_mfma_f32_16x16x32_bf16(haf[kf], whh[1][kf], acc[1], 0, 0, 0);
            acc[2] = __builtin_amdgcn_mfma_f32_16x16x32_bf16(haf[kf], whh[2][kf], acc[2], 0, 0, 0);
        }

        float rstf[4] = {1.f, 1.f, 1.f, 1.f};
        if (t > 0) {
            int4 dd = *(const int4*)&doneL[(t - 1) * 16 + 4 * lg];
            rstf[0] = dd.x ? 0.f : 1.f; rstf[1] = dd.y ? 0.f : 1.f;
            rstf[2] = dd.z ? 0.f : 1.f; rstf[3] = dd.w ? 0.f : 1.f;
        }
        float hn_[4];
#pragma unroll
        for (int r = 0; r < 4; r++) {
            float rg = __builtin_amdgcn_rcpf(1.f + __expf(-acc[0][r]));
            float zg = __builtin_amdgcn_rcpf(1.f + __expf(-acc[1][r]));
            float xn = (r == 0) ? bflo(xn8.x) : (r == 1) ? bfhi(xn8.x)
                     : (r == 2) ? bflo(xn8.y) : bfhi(xn8.y);
            float aa = fmaf(rg, acc[2][r], xn);
            float ng = 1.f - 2.f * __builtin_amdgcn_rcpf(__expf(2.f * aa) + 1.f);
            float hp = h_reg[r] * rstf[r];
            float hn = (1.f - zg) * ng + zg * hp;
            h_reg[r] = hn;                       // un-reset
            hn_[r] = hn;
        }
        {   // cvt_pk writeback (2 cvt + 2 shifts vs 16 inst of scalar f2bf)
            unsigned pk0, pk1;
            asm("v_cvt_pk_bf16_f32 %0, %1, %2" : "=v"(pk0) : "v"(hn_[0]), "v"(hn_[1]));
            asm("v_cvt_pk_bf16_f32 %0, %1, %2" : "=v"(pk1) : "v"(hn_[2]), "v"(hn_[3]));
            hTn[(4 * lg + 0) * 136 + c] = (short)pk0;
            hTn[(4 * lg + 1) * 136 + c] = (short)(pk0 >> 16);
            hTn[(4 * lg + 2) * 136 + c] = (short)pk1;
            hTn[(4 * lg + 3) * 136 + c] = (short)(pk1 >> 16);
        }
        __builtin_amdgcn_s_setprio(0);
        // raw barrier: lgkmcnt(0) only, semantic intrinsic
        __builtin_amdgcn_sched_barrier(0);
        __builtin_amdgcn_s_waitcnt(0xC07F);
        __builtin_amdgcn_s_barrier();
        __builtin_amdgcn_sched_barrier(0);
    }
    {   // epilogue FC for frame t_end-1 (slot t_end&1 holds h_{t_end-1})
        const short* hTp = &hT[t_end & 1][0];
        short8 haf[4];
#pragma unroll
        for (int kf = 0; kf < 4; kf++)
            haf[kf] = *(const short8*)&hTp[q * 136 + kf * 32 + 8 * lg];
        f32x4 fca = {cbf, cbf, cbf, cbf};
#pragma unroll
        for (int kf = 0; kf < 4; kf++)
            fca = __builtin_amdgcn_mfma_f32_16x16x32_bf16(haf[kf], wfc[kf], fca, 0, 0, 0);
#pragma unroll
        for (int r = 0; r < 4; r++) {
            int bb = 4 * lg + r;
            float v = fca[r];
            float e = __expf(v) - 1.f;
            v = v > 0.f ? v : e;
            out[(((size_t)(bg * 16 + bb)) * Tt + (t_end - 1)) * Hd + c] = v;
        }
    }
    if (ck == NCK - 1) {   // h after step 255, un-reset
#pragma unroll
        for (int r = 0; r < 4; r++) {
            int bb = 4 * lg + r;
            hlast[(size_t)(bg * 16 + bb) * Hd + c] = h_reg[r];
        }
    }
}

extern "C" void kernel_launch(void* const* d_in, const int* in_sizes, int n_in,
                              void* d_out, int out_size, void* d_ws, size_t ws_size,
                              hipStream_t stream) {
    const float* x   = (const float*)d_in[0];
    const float* h0  = (const float*)d_in[1];
    const int*   dn  = (const int*)d_in[2];
    const float* Wih = (const float*)d_in[3];
    const float* Whh = (const float*)d_in[4];
    const float* bih = (const float*)d_in[5];
    const float* bhh = (const float*)d_in[6];
    const float* fcW = (const float*)d_in[7];
    const float* fcb = (const float*)d_in[8];

    short* wIh = (short*)d_ws;                 // 96 KB
    short* wHh = wIh + 49152;                  // 96 KB
    short* wFc = wHh + 49152;                  // 32 KB
    short* xi_l = wFc + 16384;                 // full-T xi: 201 MB
    float* out = (float*)d_out;
    float* hlast = out + (size_t)Bb * Tt * Hd;

    prep_weights<<<56, 256, 0, stream>>>(Wih, Whh, fcW, wIh, wHh, wFc);
    xi_gemm<<<dim3(64, Tt / 8), 512, 0, stream>>>(x, bih, bhh, wIh, xi_l);
    gru_chunk<<<dim3(64, NCK), 512, 0, stream>>>(xi_l, dn, h0, bhh, fcb,
                                                 wHh, wFc, out, hlast);
}